// Round 15
// baseline (213.507 us; speedup 1.0000x reference)
//
#include <hip/hip_runtime.h>

#define BATCH 512
#define NI 1152
#define ND 8
#define NO 10
#define NE 16

// ---- bf16 helpers (RNE pack, shift unpack); storage-only, all math fp32 ----
__device__ __forceinline__ unsigned int bf16_rne(float f) {
    const unsigned int u = __builtin_bit_cast(unsigned int, f);
    return (u + 0x7fffu + ((u >> 16) & 1u)) >> 16;
}
__device__ __forceinline__ float bf_lo(unsigned int u) {
    return __builtin_bit_cast(float, u << 16);
}
__device__ __forceinline__ float bf_hi(unsigned int u) {
    return __builtin_bit_cast(float, u & 0xffff0000u);
}

// =====================================================================
// Two-kernel split (r15). Single-kernel r7 structure is a proven local
// optimum (121us): its einsum is capped at 16 waves/CU by the 74 KB
// priors LDS, and every deeper pipeline was RA-blocked (r8/r13/r14).
// Kernel A (pure GEMM->bf16 store): no LDS -> full occupancy, BB=4 cuts
// W L2 stream to 755 MB; write-bound at 189 MB.
// Kernel B (routing): fills LDS from ws with 9 coalesced uint4 loads,
// then r7's verified mean/squash/fused-sweep code verbatim.
// Fallback to exact r7 kernel if ws_size < 189.1 MB (branch on a
// launch-constant: graph-capture safe, same work every call).
// =====================================================================

// ------------------------- Kernel A: priors -------------------------
constexpr int A_THREADS = 512;
constexpr int A_BB      = 4;
constexpr int A_BPG     = BATCH / A_BB;   // 128
constexpr int A_QUADS   = A_THREADS / 4;  // 128
constexpr int A_ITEMS   = NI / A_QUADS;   // 9

__global__ __launch_bounds__(A_THREADS, 8)
void caps_priors(const float* __restrict__ x,
                 const float* __restrict__ Wt,
                 unsigned int* __restrict__ pws)   // [o][b][i][8] bf16x2
{
    const int o  = blockIdx.x / A_BPG;
    const int b0 = (blockIdx.x % A_BPG) * A_BB;
    const int t  = threadIdx.x;
    const int e4 = t & 3;
    const int iq = t >> 2;

    const float* xb = x  + (size_t)b0 * (NI * ND);
    const float* Wo = Wt + (size_t)o * ((size_t)NI * ND * NE);

#pragma unroll
    for (int k = 0; k < A_ITEMS; ++k) {
        const int i = iq + k * A_QUADS;
        const float4* Wp = (const float4*)(Wo + (size_t)i * (ND * NE));
        float4 wv[8];
#pragma unroll
        for (int dd = 0; dd < 8; ++dd) wv[dd] = Wp[dd * 4 + e4];
#pragma unroll
        for (int bb = 0; bb < A_BB; ++bb) {
            const float* xr = xb + (size_t)bb * (NI * ND) + (size_t)i * ND;
            const float4 xa = *(const float4*)(xr);
            const float4 xc = *(const float4*)(xr + 4);
            float4 v = make_float4(0.f, 0.f, 0.f, 0.f);
#define AD(dd, xs) { v.x += (xs)*wv[dd].x; v.y += (xs)*wv[dd].y; \
                     v.z += (xs)*wv[dd].z; v.w += (xs)*wv[dd].w; }
            AD(0, xa.x) AD(1, xa.y) AD(2, xa.z) AD(3, xa.w)
            AD(4, xc.x) AD(5, xc.y) AD(6, xc.z) AD(7, xc.w)
#undef AD
            uint2 pk;
            pk.x = bf16_rne(v.x) | (bf16_rne(v.y) << 16);
            pk.y = bf16_rne(v.z) | (bf16_rne(v.w) << 16);
            *(uint2*)(pws + (((size_t)o * BATCH + b0 + bb) * NI + i) * 8
                          + e4 * 2) = pk;   // 512 B contiguous per wave
        }
    }
}

// ------------------------- Kernel B: routing -------------------------
constexpr int THREADS = 512;
constexpr int WAVES   = THREADS / 64;   // 8
constexpr int QUADS   = THREADS / 4;    // 128
constexpr int ITEMS   = NI / QUADS;     // 9
constexpr int BB      = 2;
constexpr int BPG     = BATCH / BB;     // 256

__global__ __launch_bounds__(THREADS, 4)
void caps_routing2(const unsigned int* __restrict__ pws,
                   float* __restrict__ out)
{
    const int o  = blockIdx.x / BPG;
    const int b0 = (blockIdx.x % BPG) * BB;

    __shared__ __align__(16) unsigned int pl[BB][NI][NE / 2]; // 73728 B
    __shared__ __align__(16) float red[BB][WAVES * 16];
    __shared__ float sv[BB][16];
    __shared__ float rsum[BB][WAVES];

    const int t    = threadIdx.x;
    const int lane = t & 63;
    const int w    = t >> 6;
    const int e4   = t & 3;
    const int iq   = t >> 2;

    // ---- fill LDS: 2 x 36 KB contiguous, 9 uint4 per thread ----
    {
        const uint4* src = (const uint4*)(pws + ((size_t)o * BATCH + b0) * NI * 8);
        uint4* dst = (uint4*)&pl[0][0][0];
#pragma unroll
        for (int j = 0; j < (BB * NI * (NE / 2) / 4) / THREADS; ++j)  // 9
            dst[t + j * THREADS] = src[t + j * THREADS];
    }
    __syncthreads();

    // ---- sweep 0: mean over i (from bf16 priors, fp32 accum) ----
    float4 acc[BB];
#pragma unroll
    for (int bb = 0; bb < BB; ++bb) acc[bb] = make_float4(0.f, 0.f, 0.f, 0.f);
#pragma unroll
    for (int bb = 0; bb < BB; ++bb) {
#pragma unroll
        for (int k = 0; k < ITEMS; ++k) {
            const uint2 pk = *(const uint2*)&pl[bb][iq + k * QUADS][e4 * 2];
            acc[bb].x += bf_lo(pk.x); acc[bb].y += bf_hi(pk.x);
            acc[bb].z += bf_lo(pk.y); acc[bb].w += bf_hi(pk.y);
        }
#pragma unroll
        for (int off = 4; off <= 32; off <<= 1) {
            acc[bb].x += __shfl_xor(acc[bb].x, off);
            acc[bb].y += __shfl_xor(acc[bb].y, off);
            acc[bb].z += __shfl_xor(acc[bb].z, off);
            acc[bb].w += __shfl_xor(acc[bb].w, off);
        }
        if (lane < 4) *(float4*)&red[bb][w * 16 + e4 * 4] = acc[bb];
    }
    __syncthreads();
    if (t < 16 * BB) {
        const int bb = t >> 4, e = t & 15;
        float s = 0.f;
#pragma unroll
        for (int q = 0; q < WAVES; ++q) s += red[bb][q * 16 + e];
        sv[bb][e] = s * (1.0f / (float)NI);
    }
    __syncthreads();

    // ---- squash(s0) -> outv ----
    float4 outv[BB];
#pragma unroll
    for (int bb = 0; bb < BB; ++bb) {
        float sq = 0.f;
#pragma unroll
        for (int e = 0; e < 16; ++e) { const float vv = sv[bb][e]; sq += vv * vv; }
        const float scale = sqrtf(sq) / (1.0f + sq);
        outv[bb].x = sv[bb][e4 * 4 + 0] * scale;
        outv[bb].y = sv[bb][e4 * 4 + 1] * scale;
        outv[bb].z = sv[bb][e4 * 4 + 2] * scale;
        outv[bb].w = sv[bb][e4 * 4 + 3] * scale;
    }

    float lg[BB][ITEMS];
    // ---- routing iterations 1 and 2: fused sweep (r5-r8 validated) ----
    for (int it = 1; it < 3; ++it) {
#pragma unroll
        for (int bb = 0; bb < BB; ++bb) {
            float4 pacc = make_float4(0.f, 0.f, 0.f, 0.f);
            float  lsum = 0.f;
#pragma unroll
            for (int k = 0; k < ITEMS; ++k) {
                const uint2 pk = *(const uint2*)&pl[bb][iq + k * QUADS][e4 * 2];
                const float vx = bf_lo(pk.x), vy = bf_hi(pk.x);
                const float vz = bf_lo(pk.y), vw = bf_hi(pk.y);
                float part = vx * outv[bb].x + vy * outv[bb].y
                           + vz * outv[bb].z + vw * outv[bb].w;
                part += __shfl_xor(part, 1);
                part += __shfl_xor(part, 2);
                const float l = (it == 1) ? part : (lg[bb][k] + part);
                lg[bb][k] = l;
                const float wgt = __expf(l);   // |l| <~ 40 << 88: safe
                pacc.x += wgt * vx; pacc.y += wgt * vy;
                pacc.z += wgt * vz; pacc.w += wgt * vw;
                lsum += wgt;
            }
#pragma unroll
            for (int off = 4; off <= 32; off <<= 1) {
                pacc.x += __shfl_xor(pacc.x, off);
                pacc.y += __shfl_xor(pacc.y, off);
                pacc.z += __shfl_xor(pacc.z, off);
                pacc.w += __shfl_xor(pacc.w, off);
                lsum   += __shfl_xor(lsum, off);
            }
            if (lane < 4) *(float4*)&red[bb][w * 16 + e4 * 4] = pacc;
            if (lane == 0) rsum[bb][w] = lsum;
        }
        __syncthreads();
        if (t < 16 * BB) {
            const int bb = t >> 4, e = t & 15;
            float s = 0.f;
#pragma unroll
            for (int q = 0; q < WAVES; ++q) s += red[bb][q * 16 + e];
            float L = 0.f;
#pragma unroll
            for (int q = 0; q < WAVES; ++q) L += rsum[bb][q];
            sv[bb][e] = s / L;
        }
        __syncthreads();

        if (it == 1) {
#pragma unroll
            for (int bb = 0; bb < BB; ++bb) {
                float sq = 0.f;
#pragma unroll
                for (int e = 0; e < 16; ++e) { const float vv = sv[bb][e]; sq += vv * vv; }
                const float scale = sqrtf(sq) / (1.0f + sq);
                outv[bb].x = sv[bb][e4 * 4 + 0] * scale;
                outv[bb].y = sv[bb][e4 * 4 + 1] * scale;
                outv[bb].z = sv[bb][e4 * 4 + 2] * scale;
                outv[bb].w = sv[bb][e4 * 4 + 3] * scale;
            }
        }
    }

    if (t < 16 * BB) {
        const int bb = t >> 4, e = t & 15;
        float sq = 0.f;
#pragma unroll
        for (int ee = 0; ee < 16; ++ee) { const float vv = sv[bb][ee]; sq += vv * vv; }
        const float scale = sqrtf(sq) / (1.0f + sq);
        out[((size_t)o * BATCH + b0 + bb) * NE + e] = sv[bb][e] * scale;
    }
}

// --------------- Fallback: exact r7 kernel (121 us measured) ---------------
__global__ __launch_bounds__(THREADS, 4)
void caps_routing_fb(const float* __restrict__ x,
                     const float* __restrict__ Wt,
                     float* __restrict__ out)
{
    const int o  = blockIdx.x / BPG;
    const int b0 = (blockIdx.x % BPG) * BB;

    __shared__ __align__(16) unsigned int pl[BB][NI][NE / 2];
    __shared__ __align__(16) float red[BB][WAVES * 16];
    __shared__ float sv[BB][16];
    __shared__ float rsum[BB][WAVES];

    const int t    = threadIdx.x;
    const int lane = t & 63;
    const int w    = t >> 6;
    const int e4   = t & 3;
    const int iq   = t >> 2;

    const float* xb = x  + (size_t)b0 * (NI * ND);
    const float* Wo = Wt + (size_t)o * ((size_t)NI * ND * NE);

    float lg[BB][ITEMS];
    float4 acc[BB];
#pragma unroll
    for (int bb = 0; bb < BB; ++bb) acc[bb] = make_float4(0.f, 0.f, 0.f, 0.f);

#pragma unroll
    for (int k = 0; k < ITEMS; ++k) {
        const int i = iq + k * QUADS;
        float4 xa[BB], xc[BB];
#pragma unroll
        for (int bb = 0; bb < BB; ++bb) {
            const float* xr = xb + (size_t)bb * (NI * ND) + (size_t)i * ND;
            xa[bb] = *(const float4*)(xr);
            xc[bb] = *(const float4*)(xr + 4);
        }
        const float4* Wp = (const float4*)(Wo + (size_t)i * (ND * NE));
        float4 v[BB];
#pragma unroll
        for (int bb = 0; bb < BB; ++bb) v[bb] = make_float4(0.f, 0.f, 0.f, 0.f);
#define DSTEP(dd, FIELD, ARR) { const float4 wv = Wp[(dd)*4 + e4]; \
        _Pragma("unroll") \
        for (int bb = 0; bb < BB; ++bb) { const float xs = ARR[bb].FIELD; \
            v[bb].x += xs*wv.x; v[bb].y += xs*wv.y; \
            v[bb].z += xs*wv.z; v[bb].w += xs*wv.w; } }
        DSTEP(0, x, xa) DSTEP(1, y, xa) DSTEP(2, z, xa) DSTEP(3, w, xa)
        DSTEP(4, x, xc) DSTEP(5, y, xc) DSTEP(6, z, xc) DSTEP(7, w, xc)
#undef DSTEP
#pragma unroll
        for (int bb = 0; bb < BB; ++bb) {
            uint2 pk;
            pk.x = bf16_rne(v[bb].x) | (bf16_rne(v[bb].y) << 16);
            pk.y = bf16_rne(v[bb].z) | (bf16_rne(v[bb].w) << 16);
            *(uint2*)&pl[bb][i][e4 * 2] = pk;
            acc[bb].x += v[bb].x; acc[bb].y += v[bb].y;
            acc[bb].z += v[bb].z; acc[bb].w += v[bb].w;
        }
    }

#pragma unroll
    for (int bb = 0; bb < BB; ++bb) {
#pragma unroll
        for (int off = 4; off <= 32; off <<= 1) {
            acc[bb].x += __shfl_xor(acc[bb].x, off);
            acc[bb].y += __shfl_xor(acc[bb].y, off);
            acc[bb].z += __shfl_xor(acc[bb].z, off);
            acc[bb].w += __shfl_xor(acc[bb].w, off);
        }
        if (lane < 4) *(float4*)&red[bb][w * 16 + e4 * 4] = acc[bb];
    }
    __syncthreads();
    if (t < 16 * BB) {
        const int bb = t >> 4, e = t & 15;
        float s = 0.f;
#pragma unroll
        for (int q = 0; q < WAVES; ++q) s += red[bb][q * 16 + e];
        sv[bb][e] = s * (1.0f / (float)NI);
    }
    __syncthreads();

    float4 outv[BB];
#pragma unroll
    for (int bb = 0; bb < BB; ++bb) {
        float sq = 0.f;
#pragma unroll
        for (int e = 0; e < 16; ++e) { const float vv = sv[bb][e]; sq += vv * vv; }
        const float scale = sqrtf(sq) / (1.0f + sq);
        outv[bb].x = sv[bb][e4 * 4 + 0] * scale;
        outv[bb].y = sv[bb][e4 * 4 + 1] * scale;
        outv[bb].z = sv[bb][e4 * 4 + 2] * scale;
        outv[bb].w = sv[bb][e4 * 4 + 3] * scale;
    }

    for (int it = 1; it < 3; ++it) {
#pragma unroll
        for (int bb = 0; bb < BB; ++bb) {
            float4 pacc = make_float4(0.f, 0.f, 0.f, 0.f);
            float  lsum = 0.f;
#pragma unroll
            for (int k = 0; k < ITEMS; ++k) {
                const uint2 pk = *(const uint2*)&pl[bb][iq + k * QUADS][e4 * 2];
                const float vx = bf_lo(pk.x), vy = bf_hi(pk.x);
                const float vz = bf_lo(pk.y), vw = bf_hi(pk.y);
                float part = vx * outv[bb].x + vy * outv[bb].y
                           + vz * outv[bb].z + vw * outv[bb].w;
                part += __shfl_xor(part, 1);
                part += __shfl_xor(part, 2);
                const float l = (it == 1) ? part : (lg[bb][k] + part);
                lg[bb][k] = l;
                const float wgt = __expf(l);
                pacc.x += wgt * vx; pacc.y += wgt * vy;
                pacc.z += wgt * vz; pacc.w += wgt * vw;
                lsum += wgt;
            }
#pragma unroll
            for (int off = 4; off <= 32; off <<= 1) {
                pacc.x += __shfl_xor(pacc.x, off);
                pacc.y += __shfl_xor(pacc.y, off);
                pacc.z += __shfl_xor(pacc.z, off);
                pacc.w += __shfl_xor(pacc.w, off);
                lsum   += __shfl_xor(lsum, off);
            }
            if (lane < 4) *(float4*)&red[bb][w * 16 + e4 * 4] = pacc;
            if (lane == 0) rsum[bb][w] = lsum;
        }
        __syncthreads();
        if (t < 16 * BB) {
            const int bb = t >> 4, e = t & 15;
            float s = 0.f;
#pragma unroll
            for (int q = 0; q < WAVES; ++q) s += red[bb][q * 16 + e];
            float L = 0.f;
#pragma unroll
            for (int q = 0; q < WAVES; ++q) L += rsum[bb][q];
            sv[bb][e] = s / L;
        }
        __syncthreads();

        if (it == 1) {
#pragma unroll
            for (int bb = 0; bb < BB; ++bb) {
                float sq = 0.f;
#pragma unroll
                for (int e = 0; e < 16; ++e) { const float vv = sv[bb][e]; sq += vv * vv; }
                const float scale = sqrtf(sq) / (1.0f + sq);
                outv[bb].x = sv[bb][e4 * 4 + 0] * scale;
                outv[bb].y = sv[bb][e4 * 4 + 1] * scale;
                outv[bb].z = sv[bb][e4 * 4 + 2] * scale;
                outv[bb].w = sv[bb][e4 * 4 + 3] * scale;
            }
        }
    }

    if (t < 16 * BB) {
        const int bb = t >> 4, e = t & 15;
        float sq = 0.f;
#pragma unroll
        for (int ee = 0; ee < 16; ++ee) { const float vv = sv[bb][ee]; sq += vv * vv; }
        const float scale = sqrtf(sq) / (1.0f + sq);
        out[((size_t)o * BATCH + b0 + bb) * NE + e] = sv[bb][e] * scale;
    }
}

extern "C" void kernel_launch(void* const* d_in, const int* in_sizes, int n_in,
                              void* d_out, int out_size, void* d_ws, size_t ws_size,
                              hipStream_t stream) {
    const float* x  = (const float*)d_in[0];
    const float* Wt = (const float*)d_in[1];
    float* outp = (float*)d_out;

    const size_t need = (size_t)NO * BATCH * NI * (NE / 2) * sizeof(unsigned int);
    if (ws_size >= need) {
        unsigned int* pws = (unsigned int*)d_ws;
        caps_priors<<<dim3(NO * A_BPG), dim3(A_THREADS), 0, stream>>>(x, Wt, pws);
        caps_routing2<<<dim3(NO * BPG), dim3(THREADS), 0, stream>>>(pws, outp);
    } else {
        caps_routing_fb<<<dim3(NO * BPG), dim3(THREADS), 0, stream>>>(x, Wt, outp);
    }
}